// Round 2
// baseline (1329.121 us; speedup 1.0000x reference)
//
#include <hip/hip_runtime.h>

typedef unsigned short u16;
using bf16x8 = __attribute__((ext_vector_type(8))) short;
using f32x4  = __attribute__((ext_vector_type(4))) float;

#define CH   1024
#define NP   2048
#define CQ   128

__device__ __forceinline__ float bf2f(u16 u){
  union { unsigned u; float f; } c; c.u = ((unsigned)u) << 16; return c.f;
}
__device__ __forceinline__ u16 f2bf(float f){
  unsigned x = __float_as_uint(f);
  unsigned r = (x + 0x7fffu + ((x >> 16) & 1u)) >> 16;
  return (u16)r;
}

// Diagnostic: if workspace is too small, report its size via the absmax channel.
__global__ void ws_marker(float* out, float have_mb){
  out[0] = 1048576.0f + have_mb;
}

// ---------------------------------------------------------------------------
// Transpose+split: x [b][c][n] fp32 -> xh,xl [b][n][c] bf16 (hi/lo split)
// ---------------------------------------------------------------------------
__global__ __launch_bounds__(256) void transpose_split(const float* __restrict__ x,
                                                       u16* __restrict__ xh,
                                                       u16* __restrict__ xl){
  const int bb = blockIdx.z;
  const int n0 = blockIdx.x * 64, c0 = blockIdx.y * 64;
  __shared__ float tile[64][65];
  const int t = threadIdx.x;
  const float* xb = x + ((size_t)bb*CH + c0)*NP + n0;
#pragma unroll
  for (int rr = 0; rr < 4; ++rr){
    const int c_l = (t >> 4) + rr*16;
    const int n_l = (t & 15) * 4;
    float4 v = *(const float4*)&xb[(size_t)c_l*NP + n_l];
    tile[c_l][n_l+0] = v.x; tile[c_l][n_l+1] = v.y;
    tile[c_l][n_l+2] = v.z; tile[c_l][n_l+3] = v.w;
  }
  __syncthreads();
  u16* oh = xh + ((size_t)bb*NP + n0)*CH + c0;
  u16* ol = xl + ((size_t)bb*NP + n0)*CH + c0;
#pragma unroll
  for (int rr = 0; rr < 4; ++rr){
    const int n_l = (t >> 4) + rr*16;
    const int c_l = (t & 15) * 4;
    ushort4 h, l;
    float v0 = tile[c_l+0][n_l], v1 = tile[c_l+1][n_l];
    float v2 = tile[c_l+2][n_l], v3 = tile[c_l+3][n_l];
    h.x = f2bf(v0); l.x = f2bf(v0 - bf2f(h.x));
    h.y = f2bf(v1); l.y = f2bf(v1 - bf2f(h.y));
    h.z = f2bf(v2); l.z = f2bf(v2 - bf2f(h.z));
    h.w = f2bf(v3); l.w = f2bf(v3 - bf2f(h.w));
    *(ushort4*)&oh[(size_t)n_l*CH + c_l] = h;
    *(ushort4*)&ol[(size_t)n_l*CH + c_l] = l;
  }
}

// ---------------------------------------------------------------------------
// Split fp32 weights -> bf16 hi (+ optional lo)
// ---------------------------------------------------------------------------
__global__ void split_w(const float* __restrict__ w, u16* __restrict__ wh,
                        u16* __restrict__ wl, int n){
  int i = blockIdx.x * blockDim.x + threadIdx.x;
  const int stride = gridDim.x * blockDim.x;
  for (; i < n; i += stride){
    float v = w[i];
    u16 h = f2bf(v);
    wh[i] = h;
    if (wl) wl[i] = f2bf(v - bf2f(h));
  }
}

// ---------------------------------------------------------------------------
// Plain bf16 GEMM, both operands BT-form (rows x K, K contiguous).
// D[row,col] = sum_k A[row,k]*B[col,k]. 128x128 tile, 4 waves, 16x16x32 MFMA.
// Staging: VGPR round-trip (no global_load_lds this round — correctness A/B).
// EPI 0: BN+relu, bf16 store transposed  out[b][col][row]            (conv2)
// EPI 1: t = x1 - acc*rscale[row], bf16 row-major out[b][row][col]   (attn)
// EPI 2: BN+relu + x1 residual, fp32 store transposed out[b][col][row] (conv5)
// ---------------------------------------------------------------------------
template<int EPI>
__global__ __launch_bounds__(256) void gemm_plain(
    const u16* __restrict__ A, const u16* __restrict__ B,
    int lda, int ldb, long astr, long bstr, int K,
    void* __restrict__ out0, long ostr, int ldo,
    const float* __restrict__ pg, const float* __restrict__ pb,
    const float* __restrict__ pm, const float* __restrict__ pv,
    const u16* __restrict__ x1h, const u16* __restrict__ x1l,
    const float* __restrict__ rscale)
{
  __shared__ __align__(16) u16 sA[128*32], sB[128*32];
  const int tid  = threadIdx.x;
  const int lane = tid & 63, wave = tid >> 6;
  const int wr = wave & 1, wc = wave >> 1;
  const int l15 = lane & 15, q = lane >> 4;
  const int bb = blockIdx.z;
  const u16* Ab = A + (size_t)bb*astr + (size_t)blockIdx.x*128*lda;
  const u16* Bb = B + (size_t)bb*bstr + (size_t)blockIdx.y*128*ldb;

  f32x4 acc[4][4] = {};

  const int r0 = tid >> 2, r1 = r0 + 64;
  const int koff = (tid & 3) << 3;
  for (int kt = 0; kt < K; kt += 32){
    bf16x8 a0 = *(const bf16x8*)(Ab + (size_t)r0*lda + kt + koff);
    bf16x8 a1 = *(const bf16x8*)(Ab + (size_t)r1*lda + kt + koff);
    bf16x8 b0 = *(const bf16x8*)(Bb + (size_t)r0*ldb + kt + koff);
    bf16x8 b1 = *(const bf16x8*)(Bb + (size_t)r1*ldb + kt + koff);
    *(bf16x8*)&sA[tid*8]        = a0;
    *(bf16x8*)&sA[2048 + tid*8] = a1;
    *(bf16x8*)&sB[tid*8]        = b0;
    *(bf16x8*)&sB[2048 + tid*8] = b1;
    __syncthreads();
    bf16x8 af[4], bfr[4];
#pragma unroll
    for (int i = 0; i < 4; ++i) af[i]  = *(const bf16x8*)&sA[(wr*64 + i*16 + l15)*32 + q*8];
#pragma unroll
    for (int j = 0; j < 4; ++j) bfr[j] = *(const bf16x8*)&sB[(wc*64 + j*16 + l15)*32 + q*8];
#pragma unroll
    for (int i = 0; i < 4; ++i)
#pragma unroll
      for (int j = 0; j < 4; ++j)
        acc[i][j] = __builtin_amdgcn_mfma_f32_16x16x32_bf16(af[i], bfr[j], acc[i][j], 0, 0, 0);
    __syncthreads();
  }

  const int rbase = blockIdx.x*128 + wr*64;
  const int cbase = blockIdx.y*128 + wc*64;
#pragma unroll
  for (int j = 0; j < 4; ++j){
    const int gc = cbase + j*16 + l15;
    float scale = 0.f, bias = 0.f;
    if (EPI == 0 || EPI == 2){
      scale = pg[gc] * rsqrtf(pv[gc] + 1e-5f);
      bias  = pb[gc] - pm[gc]*scale;
    }
#pragma unroll
    for (int i = 0; i < 4; ++i){
      const int gr0 = rbase + i*16 + q*4;
      if (EPI == 0){
        ushort4 pk;
        pk.x = f2bf(fmaxf(acc[i][j][0]*scale + bias, 0.f));
        pk.y = f2bf(fmaxf(acc[i][j][1]*scale + bias, 0.f));
        pk.z = f2bf(fmaxf(acc[i][j][2]*scale + bias, 0.f));
        pk.w = f2bf(fmaxf(acc[i][j][3]*scale + bias, 0.f));
        *(ushort4*)&((u16*)out0)[(size_t)bb*ostr + (size_t)gc*ldo + gr0] = pk;
      } else if (EPI == 1){
#pragma unroll
        for (int r = 0; r < 4; ++r){
          const int gr = gr0 + r;
          const size_t idx = (size_t)bb*ostr + (size_t)gr*ldo + gc;
          const float rsv = rscale[bb*NP + gr];
          const float x1v = bf2f(x1h[idx]) + bf2f(x1l[idx]);
          ((u16*)out0)[idx] = f2bf(x1v - acc[i][j][r]*rsv);
        }
      } else {
        float4 o4;
#pragma unroll
        for (int r = 0; r < 4; ++r){
          const int gr = gr0 + r;
          const size_t xidx = (size_t)bb*((size_t)NP*CH) + (size_t)gr*CH + gc;
          const float x2  = fmaxf(acc[i][j][r]*scale + bias, 0.f);
          const float x1v = bf2f(x1h[xidx]) + bf2f(x1l[xidx]);
          (&o4.x)[r] = x1v + x2;
        }
        *(float4*)&((float*)out0)[(size_t)bb*ostr + (size_t)gc*ldo + gr0] = o4;
      }
    }
  }
}

// ---------------------------------------------------------------------------
// Split-bf16 GEMM: acc = Ah*Bh + Ah*Bl + Al*Bh  (~fp32 accuracy).
// EPI 0: BN+relu, split bf16 store row-major (conv1/3/4)
// EPI 1: raw fp32 store row-major (scores)
// ---------------------------------------------------------------------------
template<int EPI>
__global__ __launch_bounds__(256) void gemm_split3(
    const u16* __restrict__ Ah, const u16* __restrict__ Al,
    const u16* __restrict__ Bh, const u16* __restrict__ Bl,
    int lda, int ldb, long astr, long bstr, int K,
    u16* __restrict__ outH, u16* __restrict__ outL, float* __restrict__ outF,
    long ostr, int ldo,
    const float* __restrict__ pg, const float* __restrict__ pb,
    const float* __restrict__ pm, const float* __restrict__ pv)
{
  __shared__ __align__(16) u16 sAh[4096], sAl[4096], sBh[4096], sBl[4096];
  const int tid  = threadIdx.x;
  const int lane = tid & 63, wave = tid >> 6;
  const int wr = wave & 1, wc = wave >> 1;
  const int l15 = lane & 15, q = lane >> 4;
  const int bb = blockIdx.z;
  const u16* Abh = Ah + (size_t)bb*astr + (size_t)blockIdx.x*128*lda;
  const u16* Abl = Al + (size_t)bb*astr + (size_t)blockIdx.x*128*lda;
  const u16* Bbh = Bh + (size_t)bb*bstr + (size_t)blockIdx.y*128*ldb;
  const u16* Bbl = Bl + (size_t)bb*bstr + (size_t)blockIdx.y*128*ldb;

  f32x4 acc[4][4] = {};

  const int r0 = tid >> 2, r1 = r0 + 64;
  const int koff = (tid & 3) << 3;
  for (int kt = 0; kt < K; kt += 32){
    bf16x8 va0 = *(const bf16x8*)(Abh + (size_t)r0*lda + kt + koff);
    bf16x8 va1 = *(const bf16x8*)(Abh + (size_t)r1*lda + kt + koff);
    bf16x8 va2 = *(const bf16x8*)(Abl + (size_t)r0*lda + kt + koff);
    bf16x8 va3 = *(const bf16x8*)(Abl + (size_t)r1*lda + kt + koff);
    bf16x8 vb0 = *(const bf16x8*)(Bbh + (size_t)r0*ldb + kt + koff);
    bf16x8 vb1 = *(const bf16x8*)(Bbh + (size_t)r1*ldb + kt + koff);
    bf16x8 vb2 = *(const bf16x8*)(Bbl + (size_t)r0*ldb + kt + koff);
    bf16x8 vb3 = *(const bf16x8*)(Bbl + (size_t)r1*ldb + kt + koff);
    *(bf16x8*)&sAh[tid*8]        = va0;
    *(bf16x8*)&sAh[2048 + tid*8] = va1;
    *(bf16x8*)&sAl[tid*8]        = va2;
    *(bf16x8*)&sAl[2048 + tid*8] = va3;
    *(bf16x8*)&sBh[tid*8]        = vb0;
    *(bf16x8*)&sBh[2048 + tid*8] = vb1;
    *(bf16x8*)&sBl[tid*8]        = vb2;
    *(bf16x8*)&sBl[2048 + tid*8] = vb3;
    __syncthreads();
    bf16x8 ah[4], al[4], bh2[4], bl2[4];
#pragma unroll
    for (int i = 0; i < 4; ++i){
      const int o = (wr*64 + i*16 + l15)*32 + q*8;
      ah[i] = *(const bf16x8*)&sAh[o];
      al[i] = *(const bf16x8*)&sAl[o];
    }
#pragma unroll
    for (int j = 0; j < 4; ++j){
      const int o = (wc*64 + j*16 + l15)*32 + q*8;
      bh2[j] = *(const bf16x8*)&sBh[o];
      bl2[j] = *(const bf16x8*)&sBl[o];
    }
#pragma unroll
    for (int i = 0; i < 4; ++i)
#pragma unroll
      for (int j = 0; j < 4; ++j){
        acc[i][j] = __builtin_amdgcn_mfma_f32_16x16x32_bf16(ah[i], bh2[j], acc[i][j], 0, 0, 0);
        acc[i][j] = __builtin_amdgcn_mfma_f32_16x16x32_bf16(ah[i], bl2[j], acc[i][j], 0, 0, 0);
        acc[i][j] = __builtin_amdgcn_mfma_f32_16x16x32_bf16(al[i], bh2[j], acc[i][j], 0, 0, 0);
      }
    __syncthreads();
  }

  const int rbase = blockIdx.x*128 + wr*64;
  const int cbase = blockIdx.y*128 + wc*64;
#pragma unroll
  for (int j = 0; j < 4; ++j){
    const int gc = cbase + j*16 + l15;
    float scale = 0.f, bias = 0.f;
    if (EPI == 0){
      scale = pg[gc] * rsqrtf(pv[gc] + 1e-5f);
      bias  = pb[gc] - pm[gc]*scale;
    }
#pragma unroll
    for (int i = 0; i < 4; ++i){
      const int gr0 = rbase + i*16 + q*4;
#pragma unroll
      for (int r = 0; r < 4; ++r){
        const int gr = gr0 + r;
        const size_t idx = (size_t)bb*ostr + (size_t)gr*ldo + gc;
        if (EPI == 0){
          const float y = fmaxf(acc[i][j][r]*scale + bias, 0.f);
          const u16 h = f2bf(y);
          outH[idx] = h;
          outL[idx] = f2bf(y - bf2f(h));
        } else {
          outF[idx] = acc[i][j][r];
        }
      }
    }
  }
}

// ---------------------------------------------------------------------------
// Column softmax over one batch's S' [m][n] along m (stride-2048), lane-per-n.
// ---------------------------------------------------------------------------
__global__ __launch_bounds__(256) void softmax_col(const float* __restrict__ S,
                                                   u16* __restrict__ P){
  const int l  = threadIdx.x & 63;
  const int sl = threadIdx.x >> 6;
  const int nn = blockIdx.x*64 + l;
  const float* Sb = S + nn;
  float mx = -3e38f, sum = 0.f;
  for (int m = sl*512; m < sl*512 + 512; ++m){
    float s  = Sb[(size_t)m << 11];
    float nm = fmaxf(mx, s);
    sum = sum*__expf(mx - nm) + __expf(s - nm);
    mx = nm;
  }
  __shared__ float smx[4][64], ssm[4][64];
  smx[sl][l] = mx; ssm[sl][l] = sum;
  __syncthreads();
  const float gm = fmaxf(fmaxf(smx[0][l], smx[1][l]), fmaxf(smx[2][l], smx[3][l]));
  const float gs = ssm[0][l]*__expf(smx[0][l]-gm) + ssm[1][l]*__expf(smx[1][l]-gm)
                 + ssm[2][l]*__expf(smx[2][l]-gm) + ssm[3][l]*__expf(smx[3][l]-gm);
  const float inv = 1.f / gs;
  u16* Pb = P + nn;
  for (int m = sl*512; m < sl*512 + 512; ++m){
    float s = Sb[(size_t)m << 11];
    Pb[(size_t)m << 11] = f2bf(__expf(s - gm) * inv);
  }
}

// rscale[m] = 1 / (1e-9 + sum_n P[m][n]); one wave per row, one batch
__global__ __launch_bounds__(256) void rowsum(const u16* __restrict__ P,
                                              float* __restrict__ rscale){
  const int row  = blockIdx.x*4 + (threadIdx.x >> 6);
  const int lane = threadIdx.x & 63;
  const ushort4* p4 = (const ushort4*)(P + ((size_t)row << 11));
  float s = 0.f;
#pragma unroll
  for (int k = 0; k < 8; ++k){
    ushort4 v = p4[lane + k*64];
    s += bf2f(v.x) + bf2f(v.y) + bf2f(v.z) + bf2f(v.w);
  }
#pragma unroll
  for (int off = 32; off; off >>= 1) s += __shfl_down(s, off, 64);
  if (lane == 0) rscale[row] = 1.f / (1e-9f + s);
}

// ---------------------------------------------------------------------------
extern "C" void kernel_launch(void* const* d_in, const int* in_sizes, int n_in,
                              void* d_out, int out_size, void* d_ws, size_t ws_size,
                              hipStream_t stream){
  const float* x = (const float*)d_in[0];
  const float *W[5], *g[5], *bt[5], *mu[5], *vr[5];
  for (int i = 0; i < 5; ++i){
    W[i]  = (const float*)d_in[1 + 5*i + 0];
    g[i]  = (const float*)d_in[1 + 5*i + 1];
    bt[i] = (const float*)d_in[1 + 5*i + 2];
    mu[i] = (const float*)d_in[1 + 5*i + 3];
    vr[i] = (const float*)d_in[1 + 5*i + 4];
  }

  char* wp = (char*)d_ws;
  size_t off = 0;
  auto take = [&](size_t bytes) -> void* {
    void* p = wp + off;
    off = (off + bytes + 255) & ~(size_t)255;
    return p;
  };
  u16*  xh  = (u16*)take(33554432);   // x^T hi  [b][n][c]; reused as v [b][c][n]
  u16*  xl  = (u16*)take(33554432);   // x^T lo;            reused as t [b][m][c]
  u16*  x1h = (u16*)take(33554432);
  u16*  x1l = (u16*)take(33554432);
  u16*  qh  = (u16*)take(4194304);
  u16*  ql  = (u16*)take(4194304);
  u16*  kh  = (u16*)take(4194304);
  u16*  kl  = (u16*)take(4194304);
  float* S  = (float*)take(16777216); // per-batch scores, fp32 [2048][2048]
  float* rs = (float*)take(65536);
  u16*  w1h = (u16*)take(2097152);
  u16*  w1l = (u16*)take(2097152);
  u16*  w2h = (u16*)take(2097152);
  u16*  w3h = (u16*)take(262144);
  u16*  w3l = (u16*)take(262144);
  u16*  w4h = (u16*)take(262144);
  u16*  w4l = (u16*)take(262144);
  u16*  w5h = (u16*)take(2097152);

  if (ws_size < off){
    // Not enough scratch: report ws_size (MB) through the absmax channel.
    ws_marker<<<1, 1, 0, stream>>>((float*)d_out, (float)(ws_size >> 20));
    return;
  }

  u16* vh = xh;            // x dead after conv1
  u16* tt = xl;
  u16* P  = (u16*)d_out;   // 8*2048*2048 bf16 == 64 MiB == d_out size exactly;
                           // fully overwritten by conv5 at the end.

  split_w<<<dim3(256), 256, 0, stream>>>(W[0], w1h, w1l, CH*CH);
  split_w<<<dim3(256), 256, 0, stream>>>(W[1], w2h, (u16*)nullptr, CH*CH);
  split_w<<<dim3(64),  256, 0, stream>>>(W[2], w3h, w3l, CQ*CH);
  split_w<<<dim3(64),  256, 0, stream>>>(W[3], w4h, w4l, CQ*CH);
  split_w<<<dim3(256), 256, 0, stream>>>(W[4], w5h, (u16*)nullptr, CH*CH);

  transpose_split<<<dim3(32,16,8), 256, 0, stream>>>(x, xh, xl);

  // conv1: x1 = cbr(x, W1)  (split precision)
  gemm_split3<0><<<dim3(16,8,8), 256, 0, stream>>>(
      xh, xl, w1h, w1l, CH, CH, (long)NP*CH, 0, CH,
      x1h, x1l, nullptr, (long)NP*CH, CH, g[0], bt[0], mu[0], vr[0]);

  // conv3/conv4: q,k (split precision) -> [b][n][128]
  gemm_split3<0><<<dim3(16,1,8), 256, 0, stream>>>(
      x1h, x1l, w3h, w3l, CH, CH, (long)NP*CH, 0, CH,
      qh, ql, nullptr, (long)NP*CQ, CQ, g[2], bt[2], mu[2], vr[2]);
  gemm_split3<0><<<dim3(16,1,8), 256, 0, stream>>>(
      x1h, x1l, w4h, w4l, CH, CH, (long)NP*CH, 0, CH,
      kh, kl, nullptr, (long)NP*CQ, CQ, g[3], bt[3], mu[3], vr[3]);

  // attention stats per batch (S fits in 16 MB)
  for (int b = 0; b < 8; ++b){
    const size_t qo = (size_t)b*NP*CQ;
    gemm_split3<1><<<dim3(16,16,1), 256, 0, stream>>>(
        kh + qo, kl + qo, qh + qo, ql + qo, CQ, CQ, 0, 0, CQ,
        nullptr, nullptr, S, 0, NP, nullptr, nullptr, nullptr, nullptr);
    softmax_col<<<dim3(32), 256, 0, stream>>>(S, P + (size_t)b*NP*NP);
    rowsum<<<dim3(512), 256, 0, stream>>>(P + (size_t)b*NP*NP, rs + b*NP);
  }

  // conv2: v = cbr(x1, W2) -> vh [b][c][n]
  gemm_plain<0><<<dim3(16,8,8), 256, 0, stream>>>(
      x1h, w2h, CH, CH, (long)NP*CH, 0, CH,
      vh, (long)CH*NP, NP, g[1], bt[1], mu[1], vr[1], nullptr, nullptr, nullptr);

  // attn + t = x1 - attn*rscale -> tt [b][m][c]
  gemm_plain<1><<<dim3(16,8,8), 256, 0, stream>>>(
      P, vh, NP, NP, (long)NP*NP, (long)CH*NP, NP,
      tt, (long)NP*CH, CH, nullptr, nullptr, nullptr, nullptr, x1h, x1l, rs);

  // conv5 + residual -> d_out fp32 [b][c][n]
  gemm_plain<2><<<dim3(16,8,8), 256, 0, stream>>>(
      tt, w5h, CH, CH, (long)NP*CH, 0, CH,
      d_out, (long)CH*NP, NP, g[4], bt[4], mu[4], vr[4], x1h, x1l, nullptr);
}

// Round 3
// 1286.125 us; speedup vs baseline: 1.0334x; 1.0334x over previous
//
#include <hip/hip_runtime.h>

typedef unsigned short u16;
using bf16x8 = __attribute__((ext_vector_type(8))) short;
using f32x4  = __attribute__((ext_vector_type(4))) float;

#define CH   1024
#define NP   2048
#define CQ   128

__device__ __forceinline__ float bf2f(u16 u){
  union { unsigned u; float f; } c; c.u = ((unsigned)u) << 16; return c.f;
}
__device__ __forceinline__ u16 f2bf(float f){
  unsigned x = __float_as_uint(f);
  unsigned r = (x + 0x7fffu + ((x >> 16) & 1u)) >> 16;
  return (u16)r;
}

// async global->LDS, 16B/lane. Dest is wave-uniform base + lane*16 (each lane
// passes its own &s[tid*8], which equals wavebase + lane*16 — consistent).
__device__ __forceinline__ void gl2lds16(const u16* g, u16* l){
  __builtin_amdgcn_global_load_lds(
      (const __attribute__((address_space(1))) unsigned int*)(const void*)g,
      (__attribute__((address_space(3))) unsigned int*)(void*)l,
      16, 0, 0);
}

__global__ void ws_marker(float* out, float have_mb){
  out[0] = 1048576.0f + have_mb;
}

// ---------------------------------------------------------------------------
// Transpose+split: x [b][c][n] fp32 -> xh,xl [b][n][c] bf16 (hi/lo split)
// ---------------------------------------------------------------------------
__global__ __launch_bounds__(256) void transpose_split(const float* __restrict__ x,
                                                       u16* __restrict__ xh,
                                                       u16* __restrict__ xl){
  const int bb = blockIdx.z;
  const int n0 = blockIdx.x * 64, c0 = blockIdx.y * 64;
  __shared__ float tile[64][65];
  const int t = threadIdx.x;
  const float* xb = x + ((size_t)bb*CH + c0)*NP + n0;
#pragma unroll
  for (int rr = 0; rr < 4; ++rr){
    const int c_l = (t >> 4) + rr*16;
    const int n_l = (t & 15) * 4;
    float4 v = *(const float4*)&xb[(size_t)c_l*NP + n_l];
    tile[c_l][n_l+0] = v.x; tile[c_l][n_l+1] = v.y;
    tile[c_l][n_l+2] = v.z; tile[c_l][n_l+3] = v.w;
  }
  __syncthreads();
  u16* oh = xh + ((size_t)bb*NP + n0)*CH + c0;
  u16* ol = xl + ((size_t)bb*NP + n0)*CH + c0;
#pragma unroll
  for (int rr = 0; rr < 4; ++rr){
    const int n_l = (t >> 4) + rr*16;
    const int c_l = (t & 15) * 4;
    ushort4 h, l;
    float v0 = tile[c_l+0][n_l], v1 = tile[c_l+1][n_l];
    float v2 = tile[c_l+2][n_l], v3 = tile[c_l+3][n_l];
    h.x = f2bf(v0); l.x = f2bf(v0 - bf2f(h.x));
    h.y = f2bf(v1); l.y = f2bf(v1 - bf2f(h.y));
    h.z = f2bf(v2); l.z = f2bf(v2 - bf2f(h.z));
    h.w = f2bf(v3); l.w = f2bf(v3 - bf2f(h.w));
    *(ushort4*)&oh[(size_t)n_l*CH + c_l] = h;
    *(ushort4*)&ol[(size_t)n_l*CH + c_l] = l;
  }
}

// ---------------------------------------------------------------------------
// All 5 weight splits in one launch (grid.y = segment)
// ---------------------------------------------------------------------------
__global__ __launch_bounds__(256) void split_w_all(
    const float* __restrict__ w0, const float* __restrict__ w1,
    const float* __restrict__ w2, const float* __restrict__ w3,
    const float* __restrict__ w4,
    u16* h0, u16* l0, u16* h1, u16* h2, u16* l2,
    u16* h3, u16* l3, u16* h4){
  const int seg = blockIdx.y;
  const float* w; u16 *wh, *wl; int n;
  switch (seg){
    case 0:  w = w0; wh = h0; wl = l0;      n = CH*CH; break;
    case 1:  w = w1; wh = h1; wl = nullptr; n = CH*CH; break;
    case 2:  w = w2; wh = h2; wl = l2;      n = CQ*CH; break;
    case 3:  w = w3; wh = h3; wl = l3;      n = CQ*CH; break;
    default: w = w4; wh = h4; wl = nullptr; n = CH*CH; break;
  }
  for (int i = blockIdx.x*blockDim.x + threadIdx.x; i < n; i += gridDim.x*blockDim.x){
    float v = w[i];
    u16 h = f2bf(v);
    wh[i] = h;
    if (wl) wl[i] = f2bf(v - bf2f(h));
  }
}

// ---------------------------------------------------------------------------
// Plain bf16 GEMM, both operands BT-form. 128x128 tile, 16x16x32 MFMA.
// global_load_lds staging + XOR-swizzled chunk layout (bank-conflict-free).
// EPI 0: BN+relu, bf16 store transposed  out[b][col][row]             (conv2)
// EPI 1: t = x1 - acc*rscale[row], bf16 row-major out[b][row][col]    (attn)
// EPI 2: BN+relu + x1 residual, fp32 store transposed out[b][col][row] (conv5)
// ---------------------------------------------------------------------------
template<int EPI>
__global__ __launch_bounds__(256) void gemm_plain(
    const u16* __restrict__ A, const u16* __restrict__ B,
    int lda, int ldb, long astr, long bstr, int K,
    void* __restrict__ out0, long ostr, int ldo,
    const float* __restrict__ pg, const float* __restrict__ pb,
    const float* __restrict__ pm, const float* __restrict__ pv,
    const u16* __restrict__ x1h, const u16* __restrict__ x1l,
    const float* __restrict__ rscale)
{
  __shared__ __align__(16) u16 sA[4096], sB[4096];
  const int tid  = threadIdx.x;
  const int lane = tid & 63, wave = tid >> 6;
  const int wr = wave & 1, wc = wave >> 1;
  const int l15 = lane & 15, q = lane >> 4;
  const int bb = blockIdx.z;
  const u16* Ab = A + (size_t)bb*astr + (size_t)blockIdx.x*128*lda;
  const u16* Bb = B + (size_t)bb*bstr + (size_t)blockIdx.y*128*ldb;

  f32x4 acc[4][4] = {};

  const int r0 = tid >> 2, r1 = r0 + 64;
  // swizzle: LDS chunk position p of row r holds global chunk p ^ ((r>>1)&3)
  const int cs = (((tid & 3) ^ ((r0 >> 1) & 3)) << 3);

  int offA[4], offB[4];
#pragma unroll
  for (int i = 0; i < 4; ++i){
    const int ra = wr*64 + i*16 + l15;
    offA[i] = ra*32 + ((q ^ ((ra >> 1) & 3)) << 3);
    const int rb = wc*64 + i*16 + l15;
    offB[i] = rb*32 + ((q ^ ((rb >> 1) & 3)) << 3);
  }

  for (int kt = 0; kt < K; kt += 32){
    gl2lds16(Ab + (size_t)r0*lda + kt + cs, &sA[tid*8]);
    gl2lds16(Ab + (size_t)r1*lda + kt + cs, &sA[2048 + tid*8]);
    gl2lds16(Bb + (size_t)r0*ldb + kt + cs, &sB[tid*8]);
    gl2lds16(Bb + (size_t)r1*ldb + kt + cs, &sB[2048 + tid*8]);
    __syncthreads();
    bf16x8 af[4], bfr[4];
#pragma unroll
    for (int i = 0; i < 4; ++i) af[i]  = *(const bf16x8*)&sA[offA[i]];
#pragma unroll
    for (int j = 0; j < 4; ++j) bfr[j] = *(const bf16x8*)&sB[offB[j]];
#pragma unroll
    for (int i = 0; i < 4; ++i)
#pragma unroll
      for (int j = 0; j < 4; ++j)
        acc[i][j] = __builtin_amdgcn_mfma_f32_16x16x32_bf16(af[i], bfr[j], acc[i][j], 0, 0, 0);
    __syncthreads();
  }

  const int rbase = blockIdx.x*128 + wr*64;
  const int cbase = blockIdx.y*128 + wc*64;
#pragma unroll
  for (int j = 0; j < 4; ++j){
    const int gc = cbase + j*16 + l15;
    float scale = 0.f, bias = 0.f;
    if (EPI == 0 || EPI == 2){
      scale = pg[gc] * rsqrtf(pv[gc] + 1e-5f);
      bias  = pb[gc] - pm[gc]*scale;
    }
#pragma unroll
    for (int i = 0; i < 4; ++i){
      const int gr0 = rbase + i*16 + q*4;
      if (EPI == 0){
        ushort4 pk;
        pk.x = f2bf(fmaxf(acc[i][j][0]*scale + bias, 0.f));
        pk.y = f2bf(fmaxf(acc[i][j][1]*scale + bias, 0.f));
        pk.z = f2bf(fmaxf(acc[i][j][2]*scale + bias, 0.f));
        pk.w = f2bf(fmaxf(acc[i][j][3]*scale + bias, 0.f));
        *(ushort4*)&((u16*)out0)[(size_t)bb*ostr + (size_t)gc*ldo + gr0] = pk;
      } else if (EPI == 1){
#pragma unroll
        for (int r = 0; r < 4; ++r){
          const int gr = gr0 + r;
          const size_t idx = (size_t)bb*ostr + (size_t)gr*ldo + gc;
          const float rsv = rscale[bb*NP + gr];
          const float x1v = bf2f(x1h[idx]) + bf2f(x1l[idx]);
          ((u16*)out0)[idx] = f2bf(x1v - acc[i][j][r]*rsv);
        }
      } else {
        float4 o4;
#pragma unroll
        for (int r = 0; r < 4; ++r){
          const int gr = gr0 + r;
          const size_t xidx = (size_t)bb*((size_t)NP*CH) + (size_t)gr*CH + gc;
          const float x2  = fmaxf(acc[i][j][r]*scale + bias, 0.f);
          const float x1v = bf2f(x1h[xidx]) + bf2f(x1l[xidx]);
          (&o4.x)[r] = x1v + x2;
        }
        *(float4*)&((float*)out0)[(size_t)bb*ostr + (size_t)gc*ldo + gr0] = o4;
      }
    }
  }
}

// ---------------------------------------------------------------------------
// Split-bf16 GEMM: acc = Ah*Bh + Ah*Bl + Al*Bh  (~fp32 accuracy).
// EPI 0: BN+relu, split bf16 store row-major (conv1/3/4)
// EPI 1: raw fp32 store row-major (scores)
// ---------------------------------------------------------------------------
template<int EPI>
__global__ __launch_bounds__(256) void gemm_split3(
    const u16* __restrict__ Ah, const u16* __restrict__ Al,
    const u16* __restrict__ Bh, const u16* __restrict__ Bl,
    int lda, int ldb, long astr, long bstr, int K,
    u16* __restrict__ outH, u16* __restrict__ outL, float* __restrict__ outF,
    long ostr, int ldo,
    const float* __restrict__ pg, const float* __restrict__ pb,
    const float* __restrict__ pm, const float* __restrict__ pv)
{
  __shared__ __align__(16) u16 sAh[4096], sAl[4096], sBh[4096], sBl[4096];
  const int tid  = threadIdx.x;
  const int lane = tid & 63, wave = tid >> 6;
  const int wr = wave & 1, wc = wave >> 1;
  const int l15 = lane & 15, q = lane >> 4;
  const int bb = blockIdx.z;
  const u16* Abh = Ah + (size_t)bb*astr + (size_t)blockIdx.x*128*lda;
  const u16* Abl = Al + (size_t)bb*astr + (size_t)blockIdx.x*128*lda;
  const u16* Bbh = Bh + (size_t)bb*bstr + (size_t)blockIdx.y*128*ldb;
  const u16* Bbl = Bl + (size_t)bb*bstr + (size_t)blockIdx.y*128*ldb;

  f32x4 acc[4][4] = {};

  const int r0 = tid >> 2, r1 = r0 + 64;
  const int cs = (((tid & 3) ^ ((r0 >> 1) & 3)) << 3);

  int offA[4], offB[4];
#pragma unroll
  for (int i = 0; i < 4; ++i){
    const int ra = wr*64 + i*16 + l15;
    offA[i] = ra*32 + ((q ^ ((ra >> 1) & 3)) << 3);
    const int rb = wc*64 + i*16 + l15;
    offB[i] = rb*32 + ((q ^ ((rb >> 1) & 3)) << 3);
  }

  for (int kt = 0; kt < K; kt += 32){
    gl2lds16(Abh + (size_t)r0*lda + kt + cs, &sAh[tid*8]);
    gl2lds16(Abh + (size_t)r1*lda + kt + cs, &sAh[2048 + tid*8]);
    gl2lds16(Abl + (size_t)r0*lda + kt + cs, &sAl[tid*8]);
    gl2lds16(Abl + (size_t)r1*lda + kt + cs, &sAl[2048 + tid*8]);
    gl2lds16(Bbh + (size_t)r0*ldb + kt + cs, &sBh[tid*8]);
    gl2lds16(Bbh + (size_t)r1*ldb + kt + cs, &sBh[2048 + tid*8]);
    gl2lds16(Bbl + (size_t)r0*ldb + kt + cs, &sBl[tid*8]);
    gl2lds16(Bbl + (size_t)r1*ldb + kt + cs, &sBl[2048 + tid*8]);
    __syncthreads();
    bf16x8 ah[4], al[4], bh2[4], bl2[4];
#pragma unroll
    for (int i = 0; i < 4; ++i){
      ah[i] = *(const bf16x8*)&sAh[offA[i]];
      al[i] = *(const bf16x8*)&sAl[offA[i]];
    }
#pragma unroll
    for (int j = 0; j < 4; ++j){
      bh2[j] = *(const bf16x8*)&sBh[offB[j]];
      bl2[j] = *(const bf16x8*)&sBl[offB[j]];
    }
#pragma unroll
    for (int i = 0; i < 4; ++i)
#pragma unroll
      for (int j = 0; j < 4; ++j){
        acc[i][j] = __builtin_amdgcn_mfma_f32_16x16x32_bf16(ah[i], bh2[j], acc[i][j], 0, 0, 0);
        acc[i][j] = __builtin_amdgcn_mfma_f32_16x16x32_bf16(ah[i], bl2[j], acc[i][j], 0, 0, 0);
        acc[i][j] = __builtin_amdgcn_mfma_f32_16x16x32_bf16(al[i], bh2[j], acc[i][j], 0, 0, 0);
      }
    __syncthreads();
  }

  const int rbase = blockIdx.x*128 + wr*64;
  const int cbase = blockIdx.y*128 + wc*64;
#pragma unroll
  for (int j = 0; j < 4; ++j){
    const int gc = cbase + j*16 + l15;
    float scale = 0.f, bias = 0.f;
    if (EPI == 0){
      scale = pg[gc] * rsqrtf(pv[gc] + 1e-5f);
      bias  = pb[gc] - pm[gc]*scale;
    }
#pragma unroll
    for (int i = 0; i < 4; ++i){
      const int gr0 = rbase + i*16 + q*4;
#pragma unroll
      for (int r = 0; r < 4; ++r){
        const int gr = gr0 + r;
        const size_t idx = (size_t)bb*ostr + (size_t)gr*ldo + gc;
        if (EPI == 0){
          const float y = fmaxf(acc[i][j][r]*scale + bias, 0.f);
          const u16 h = f2bf(y);
          outH[idx] = h;
          outL[idx] = f2bf(y - bf2f(h));
        } else {
          outF[idx] = acc[i][j][r];
        }
      }
    }
  }
}

// ---------------------------------------------------------------------------
// Column softmax over S' [m][n] along m (stride-2048), lane-per-n.
// blockIdx.y = batch (stride 2048*2048 on both S and P).
// ---------------------------------------------------------------------------
__global__ __launch_bounds__(256) void softmax_col(const float* __restrict__ S,
                                                   u16* __restrict__ P){
  const int l  = threadIdx.x & 63;
  const int sl = threadIdx.x >> 6;
  const int nn = blockIdx.x*64 + l;
  const size_t bo = ((size_t)blockIdx.y) << 22;
  const float* Sb = S + bo + nn;
  float mx = -3e38f, sum = 0.f;
  for (int m = sl*512; m < sl*512 + 512; ++m){
    float s  = Sb[(size_t)m << 11];
    float nm = fmaxf(mx, s);
    sum = sum*__expf(mx - nm) + __expf(s - nm);
    mx = nm;
  }
  __shared__ float smx[4][64], ssm[4][64];
  smx[sl][l] = mx; ssm[sl][l] = sum;
  __syncthreads();
  const float gm = fmaxf(fmaxf(smx[0][l], smx[1][l]), fmaxf(smx[2][l], smx[3][l]));
  const float gs = ssm[0][l]*__expf(smx[0][l]-gm) + ssm[1][l]*__expf(smx[1][l]-gm)
                 + ssm[2][l]*__expf(smx[2][l]-gm) + ssm[3][l]*__expf(smx[3][l]-gm);
  const float inv = 1.f / gs;
  u16* Pb = P + bo + nn;
  for (int m = sl*512; m < sl*512 + 512; ++m){
    float s = Sb[(size_t)m << 11];
    Pb[(size_t)m << 11] = f2bf(__expf(s - gm) * inv);
  }
}

// rscale[row] = 1 / (1e-9 + sum_n P[row][n]); flat over b*m rows
__global__ __launch_bounds__(256) void rowsum(const u16* __restrict__ P,
                                              float* __restrict__ rscale){
  const int row  = blockIdx.x*4 + (threadIdx.x >> 6);
  const int lane = threadIdx.x & 63;
  const ushort4* p4 = (const ushort4*)(P + ((size_t)row << 11));
  float s = 0.f;
#pragma unroll
  for (int k = 0; k < 8; ++k){
    ushort4 v = p4[lane + k*64];
    s += bf2f(v.x) + bf2f(v.y) + bf2f(v.z) + bf2f(v.w);
  }
#pragma unroll
  for (int off = 32; off; off >>= 1) s += __shfl_down(s, off, 64);
  if (lane == 0) rscale[row] = 1.f / (1e-9f + s);
}

// ---------------------------------------------------------------------------
extern "C" void kernel_launch(void* const* d_in, const int* in_sizes, int n_in,
                              void* d_out, int out_size, void* d_ws, size_t ws_size,
                              hipStream_t stream){
  const float* x = (const float*)d_in[0];
  const float *W[5], *g[5], *bt[5], *mu[5], *vr[5];
  for (int i = 0; i < 5; ++i){
    W[i]  = (const float*)d_in[1 + 5*i + 0];
    g[i]  = (const float*)d_in[1 + 5*i + 1];
    bt[i] = (const float*)d_in[1 + 5*i + 2];
    mu[i] = (const float*)d_in[1 + 5*i + 3];
    vr[i] = (const float*)d_in[1 + 5*i + 4];
  }

  char* wp = (char*)d_ws;
  size_t off = 0;
  auto take = [&](size_t bytes) -> void* {
    void* p = wp + off;
    off = (off + bytes + 255) & ~(size_t)255;
    return p;
  };
  u16*  xh  = (u16*)take(33554432);   // x^T hi [b][n][c]; reused as v [b][c][n]
  u16*  xl  = (u16*)take(33554432);   // x^T lo;           reused as t [b][m][c]
  u16*  x1h = (u16*)take(33554432);
  u16*  x1l = (u16*)take(33554432);
  u16*  qh  = (u16*)take(4194304);
  u16*  ql  = (u16*)take(4194304);
  u16*  kh  = (u16*)take(4194304);
  u16*  kl  = (u16*)take(4194304);
  float* S  = (float*)take(16777216); // per-batch scores fp32 [2048][2048]
  float* rs = (float*)take(65536);
  u16*  w1h = (u16*)take(2097152);
  u16*  w1l = (u16*)take(2097152);
  u16*  w2h = (u16*)take(2097152);
  u16*  w3h = (u16*)take(262144);
  u16*  w3l = (u16*)take(262144);
  u16*  w4h = (u16*)take(262144);
  u16*  w4l = (u16*)take(262144);
  u16*  w5h = (u16*)take(2097152);

  if (ws_size < off){
    ws_marker<<<1, 1, 0, stream>>>((float*)d_out, (float)(ws_size >> 20));
    return;
  }

  // Batched-stats path if a full 8-batch fp32 S fits (branch on per-session
  // constant ws_size — identical work every call, graph-safe).
  float* S_all = nullptr;
  const size_t need_sall = (size_t)8 * NP * NP * 4;
  if (ws_size >= off + need_sall) S_all = (float*)take(need_sall);

  u16* vh = xh;            // x dead after conv1
  u16* tt = xl;
  u16* P  = (u16*)d_out;   // 64 MiB bf16, fully overwritten by conv5 later

  split_w_all<<<dim3(256, 5), 256, 0, stream>>>(
      W[0], W[1], W[2], W[3], W[4],
      w1h, w1l, w2h, w3h, w3l, w4h, w4l, w5h);

  transpose_split<<<dim3(32,16,8), 256, 0, stream>>>(x, xh, xl);

  // conv1: x1 = cbr(x, W1)  (split precision)
  gemm_split3<0><<<dim3(16,8,8), 256, 0, stream>>>(
      xh, xl, w1h, w1l, CH, CH, (long)NP*CH, 0, CH,
      x1h, x1l, nullptr, (long)NP*CH, CH, g[0], bt[0], mu[0], vr[0]);

  // conv3/conv4: q,k (split precision) -> [b][n][128]
  gemm_split3<0><<<dim3(16,1,8), 256, 0, stream>>>(
      x1h, x1l, w3h, w3l, CH, CH, (long)NP*CH, 0, CH,
      qh, ql, nullptr, (long)NP*CQ, CQ, g[2], bt[2], mu[2], vr[2]);
  gemm_split3<0><<<dim3(16,1,8), 256, 0, stream>>>(
      x1h, x1l, w4h, w4l, CH, CH, (long)NP*CH, 0, CH,
      kh, kl, nullptr, (long)NP*CQ, CQ, g[3], bt[3], mu[3], vr[3]);

  if (S_all){
    // scores for all batches, then batched softmax
    gemm_split3<1><<<dim3(16,16,8), 256, 0, stream>>>(
        kh, kl, qh, ql, CQ, CQ, (long)NP*CQ, (long)NP*CQ, CQ,
        nullptr, nullptr, S_all, (long)NP*NP, NP, nullptr, nullptr, nullptr, nullptr);
    softmax_col<<<dim3(32, 8), 256, 0, stream>>>(S_all, P);
  } else {
    for (int b = 0; b < 8; ++b){
      const size_t qo = (size_t)b*NP*CQ;
      gemm_split3<1><<<dim3(16,16,1), 256, 0, stream>>>(
          kh + qo, kl + qo, qh + qo, ql + qo, CQ, CQ, 0, 0, CQ,
          nullptr, nullptr, S, 0, NP, nullptr, nullptr, nullptr, nullptr);
      softmax_col<<<dim3(32, 1), 256, 0, stream>>>(S, P + (size_t)b*NP*NP);
    }
  }
  rowsum<<<dim3(4096), 256, 0, stream>>>(P, rs);

  // conv2: v = cbr(x1, W2) -> vh [b][c][n]
  gemm_plain<0><<<dim3(16,8,8), 256, 0, stream>>>(
      x1h, w2h, CH, CH, (long)NP*CH, 0, CH,
      vh, (long)CH*NP, NP, g[1], bt[1], mu[1], vr[1], nullptr, nullptr, nullptr);

  // attn + t = x1 - attn*rscale -> tt [b][m][c]
  gemm_plain<1><<<dim3(16,8,8), 256, 0, stream>>>(
      P, vh, NP, NP, (long)NP*NP, (long)CH*NP, NP,
      tt, (long)NP*CH, CH, nullptr, nullptr, nullptr, nullptr, x1h, x1l, rs);

  // conv5 + residual -> d_out fp32 [b][c][n]
  gemm_plain<2><<<dim3(16,8,8), 256, 0, stream>>>(
      tt, w5h, CH, CH, (long)NP*CH, 0, CH,
      d_out, (long)CH*NP, NP, g[4], bt[4], mu[4], vr[4], x1h, x1l, nullptr);
}

// Round 4
// 816.058 us; speedup vs baseline: 1.6287x; 1.5760x over previous
//
#include <hip/hip_runtime.h>

typedef unsigned short u16;
using bf16x8 = __attribute__((ext_vector_type(8))) short;
using f32x4  = __attribute__((ext_vector_type(4))) float;

#define CH   1024
#define NP   2048
#define CQ   128

__device__ __forceinline__ float bf2f(u16 u){
  union { unsigned u; float f; } c; c.u = ((unsigned)u) << 16; return c.f;
}
__device__ __forceinline__ u16 f2bf(float f){
  unsigned x = __float_as_uint(f);
  unsigned r = (x + 0x7fffu + ((x >> 16) & 1u)) >> 16;
  return (u16)r;
}

__device__ __forceinline__ void gl2lds16(const u16* g, u16* l){
  __builtin_amdgcn_global_load_lds(
      (const __attribute__((address_space(1))) unsigned int*)(const void*)g,
      (__attribute__((address_space(3))) unsigned int*)(void*)l,
      16, 0, 0);
}

__global__ void ws_marker(float* out, float have_mb){
  out[0] = 1048576.0f + have_mb;
}

// ---------------------------------------------------------------------------
// Transpose+split: x [b][c][n] fp32 -> xh,xl [b][n][c] bf16 (hi/lo split)
// ---------------------------------------------------------------------------
__global__ __launch_bounds__(256) void transpose_split(const float* __restrict__ x,
                                                       u16* __restrict__ xh,
                                                       u16* __restrict__ xl){
  const int bb = blockIdx.z;
  const int n0 = blockIdx.x * 64, c0 = blockIdx.y * 64;
  __shared__ float tile[64][65];
  const int t = threadIdx.x;
  const float* xb = x + ((size_t)bb*CH + c0)*NP + n0;
#pragma unroll
  for (int rr = 0; rr < 4; ++rr){
    const int c_l = (t >> 4) + rr*16;
    const int n_l = (t & 15) * 4;
    float4 v = *(const float4*)&xb[(size_t)c_l*NP + n_l];
    tile[c_l][n_l+0] = v.x; tile[c_l][n_l+1] = v.y;
    tile[c_l][n_l+2] = v.z; tile[c_l][n_l+3] = v.w;
  }
  __syncthreads();
  u16* oh = xh + ((size_t)bb*NP + n0)*CH + c0;
  u16* ol = xl + ((size_t)bb*NP + n0)*CH + c0;
#pragma unroll
  for (int rr = 0; rr < 4; ++rr){
    const int n_l = (t >> 4) + rr*16;
    const int c_l = (t & 15) * 4;
    ushort4 h, l;
    float v0 = tile[c_l+0][n_l], v1 = tile[c_l+1][n_l];
    float v2 = tile[c_l+2][n_l], v3 = tile[c_l+3][n_l];
    h.x = f2bf(v0); l.x = f2bf(v0 - bf2f(h.x));
    h.y = f2bf(v1); l.y = f2bf(v1 - bf2f(h.y));
    h.z = f2bf(v2); l.z = f2bf(v2 - bf2f(h.z));
    h.w = f2bf(v3); l.w = f2bf(v3 - bf2f(h.w));
    *(ushort4*)&oh[(size_t)n_l*CH + c_l] = h;
    *(ushort4*)&ol[(size_t)n_l*CH + c_l] = l;
  }
}

// ---------------------------------------------------------------------------
// Prep: weight splits (w3/w4 stacked into w34), BN-param concat, colsum zero.
// grid.y = segment 0..6
// ---------------------------------------------------------------------------
__global__ __launch_bounds__(256) void prep_all(
    const float* __restrict__ w0, const float* __restrict__ w1,
    const float* __restrict__ w2, const float* __restrict__ w3,
    const float* __restrict__ w4,
    u16* w1h, u16* w1l, u16* w2h,
    u16* w34h, u16* w34l, u16* w5h,
    const float* g3, const float* b3, const float* m3, const float* v3,
    const float* g4, const float* b4, const float* m4, const float* v4,
    float* p34, float* colsum){
  const int seg = blockIdx.y;
  if (seg == 5){
    for (int i = blockIdx.x*blockDim.x + threadIdx.x; i < 1024; i += gridDim.x*blockDim.x){
      const int grp = i >> 8, j = i & 255;
      const float* pa = (grp==0) ? g3 : (grp==1) ? b3 : (grp==2) ? m3 : v3;
      const float* pb = (grp==0) ? g4 : (grp==1) ? b4 : (grp==2) ? m4 : v4;
      p34[i] = (j < 128) ? pa[j] : pb[j-128];
    }
    return;
  }
  if (seg == 6){
    for (int i = blockIdx.x*blockDim.x + threadIdx.x; i < 8*NP; i += gridDim.x*blockDim.x)
      colsum[i] = 0.f;
    return;
  }
  const float* w; u16 *wh, *wl; int n;
  switch (seg){
    case 0:  w = w0; wh = w1h;           wl = w1l;           n = CH*CH; break;
    case 1:  w = w1; wh = w2h;           wl = nullptr;       n = CH*CH; break;
    case 2:  w = w2; wh = w34h;          wl = w34l;          n = CQ*CH; break;
    case 3:  w = w3; wh = w34h + CQ*CH;  wl = w34l + CQ*CH;  n = CQ*CH; break;
    default: w = w4; wh = w5h;           wl = nullptr;       n = CH*CH; break;
  }
  for (int i = blockIdx.x*blockDim.x + threadIdx.x; i < n; i += gridDim.x*blockDim.x){
    float v = w[i];
    u16 h = f2bf(v);
    wh[i] = h;
    if (wl) wl[i] = f2bf(v - bf2f(h));
  }
}

// ---------------------------------------------------------------------------
// Plain bf16 GEMM, BT-form operands, 128x128 tile, BK=64 (half the barriers).
// Swizzle: row r of a tile stores k-chunk c (16B) at position c ^ (r&7).
// EPI 0: BN+relu, bf16 store transposed  out[b][col][row]             (conv2)
// EPI 1: t = x1 - acc*rscale[row], bf16 row-major out[b][row][col]    (attn)
// EPI 2: BN+relu + x1 residual, fp32 store transposed out[b][col][row] (conv5)
// ---------------------------------------------------------------------------
template<int EPI>
__global__ __launch_bounds__(256, 4) void gemm_plain(
    const u16* __restrict__ A, const u16* __restrict__ B,
    int lda, int ldb, long astr, long bstr, int K,
    void* __restrict__ out0, long ostr, int ldo,
    const float* __restrict__ pg, const float* __restrict__ pb,
    const float* __restrict__ pm, const float* __restrict__ pv,
    const u16* __restrict__ x1h, const u16* __restrict__ x1l,
    const float* __restrict__ rscale)
{
  __shared__ __align__(16) u16 sA[8192], sB[8192];   // 128 rows x 64 k
  const int tid  = threadIdx.x;
  const int lane = tid & 63, wave = tid >> 6;
  const int wr = wave & 1, wc = wave >> 1;
  const int l15 = lane & 15, q = lane >> 4;
  const int bb = blockIdx.z;
  const u16* Ab = A + (size_t)bb*astr + (size_t)blockIdx.x*128*lda;
  const u16* Bb = B + (size_t)bb*bstr + (size_t)blockIdx.y*128*ldb;

  f32x4 acc[4][4] = {};

  const int srow = tid >> 3;       // 0..31 (row within 32-row round)
  const int schunk = tid & 7;      // 16B chunk 0..7

  for (int kt = 0; kt < K; kt += 64){
#pragma unroll
    for (int r = 0; r < 4; ++r){
      const int row = r*32 + srow;
      const int gc8 = ((schunk ^ (row & 7)) << 3);
      gl2lds16(Ab + (size_t)row*lda + kt + gc8, &sA[r*2048 + tid*8]);
      gl2lds16(Bb + (size_t)row*ldb + kt + gc8, &sB[r*2048 + tid*8]);
    }
    __syncthreads();
#pragma unroll
    for (int s = 0; s < 2; ++s){
      bf16x8 af[4], bfr[4];
#pragma unroll
      for (int i = 0; i < 4; ++i){
        const int ra = wr*64 + i*16 + l15;
        af[i]  = *(const bf16x8*)&sA[ra*64 + (((s*4 + q) ^ (ra & 7)) << 3)];
        const int rb = wc*64 + i*16 + l15;
        bfr[i] = *(const bf16x8*)&sB[rb*64 + (((s*4 + q) ^ (rb & 7)) << 3)];
      }
#pragma unroll
      for (int i = 0; i < 4; ++i)
#pragma unroll
        for (int j = 0; j < 4; ++j)
          acc[i][j] = __builtin_amdgcn_mfma_f32_16x16x32_bf16(af[i], bfr[j], acc[i][j], 0, 0, 0);
    }
    __syncthreads();
  }

  const int rbase = blockIdx.x*128 + wr*64;
  const int cbase = blockIdx.y*128 + wc*64;
#pragma unroll
  for (int j = 0; j < 4; ++j){
    const int gc = cbase + j*16 + l15;
    float scale = 0.f, bias = 0.f;
    if (EPI == 0 || EPI == 2){
      scale = pg[gc] * rsqrtf(pv[gc] + 1e-5f);
      bias  = pb[gc] - pm[gc]*scale;
    }
#pragma unroll
    for (int i = 0; i < 4; ++i){
      const int gr0 = rbase + i*16 + q*4;
      if (EPI == 0){
        ushort4 pk;
        pk.x = f2bf(fmaxf(acc[i][j][0]*scale + bias, 0.f));
        pk.y = f2bf(fmaxf(acc[i][j][1]*scale + bias, 0.f));
        pk.z = f2bf(fmaxf(acc[i][j][2]*scale + bias, 0.f));
        pk.w = f2bf(fmaxf(acc[i][j][3]*scale + bias, 0.f));
        *(ushort4*)&((u16*)out0)[(size_t)bb*ostr + (size_t)gc*ldo + gr0] = pk;
      } else if (EPI == 1){
#pragma unroll
        for (int r = 0; r < 4; ++r){
          const int gr = gr0 + r;
          const size_t idx = (size_t)bb*ostr + (size_t)gr*ldo + gc;
          const float rsv = rscale[bb*NP + gr];
          const float x1v = bf2f(x1h[idx]) + bf2f(x1l[idx]);
          ((u16*)out0)[idx] = f2bf(x1v - acc[i][j][r]*rsv);
        }
      } else {
        float4 o4;
#pragma unroll
        for (int r = 0; r < 4; ++r){
          const int gr = gr0 + r;
          const size_t xidx = (size_t)bb*((size_t)NP*CH) + (size_t)gr*CH + gc;
          const float x2  = fmaxf(acc[i][j][r]*scale + bias, 0.f);
          const float x1v = bf2f(x1h[xidx]) + bf2f(x1l[xidx]);
          (&o4.x)[r] = x1v + x2;
        }
        *(float4*)&((float*)out0)[(size_t)bb*ostr + (size_t)gc*ldo + gr0] = o4;
      }
    }
  }
}

// ---------------------------------------------------------------------------
// Split-bf16 GEMM: acc = Ah*Bh + Ah*Bl + Al*Bh (~fp32 accuracy). BK=32.
// EPI 0: BN+relu, split bf16 store row-major (conv1 / conv34)
// EPI 1: expS = exp(acc) fp32 store + per-column sum atomics (scores)
// ---------------------------------------------------------------------------
template<int EPI>
__global__ __launch_bounds__(256, 4) void gemm_split3(
    const u16* __restrict__ Ah, const u16* __restrict__ Al,
    const u16* __restrict__ Bh, const u16* __restrict__ Bl,
    int lda, int ldb, long astr, long bstr, int K,
    u16* __restrict__ outH, u16* __restrict__ outL, float* __restrict__ outF,
    long ostr, int ldo,
    const float* __restrict__ pg, const float* __restrict__ pb,
    const float* __restrict__ pm, const float* __restrict__ pv,
    float* __restrict__ colsum)
{
  __shared__ __align__(16) u16 sAh[4096], sAl[4096], sBh[4096], sBl[4096];
  const int tid  = threadIdx.x;
  const int lane = tid & 63, wave = tid >> 6;
  const int wr = wave & 1, wc = wave >> 1;
  const int l15 = lane & 15, q = lane >> 4;
  const int bb = blockIdx.z;
  const u16* Abh = Ah + (size_t)bb*astr + (size_t)blockIdx.x*128*lda;
  const u16* Abl = Al + (size_t)bb*astr + (size_t)blockIdx.x*128*lda;
  const u16* Bbh = Bh + (size_t)bb*bstr + (size_t)blockIdx.y*128*ldb;
  const u16* Bbl = Bl + (size_t)bb*bstr + (size_t)blockIdx.y*128*ldb;

  f32x4 acc[4][4] = {};

  const int r0 = tid >> 2, r1 = r0 + 64;
  const int cs = (((tid & 3) ^ ((r0 >> 1) & 3)) << 3);

  int offA[4], offB[4];
#pragma unroll
  for (int i = 0; i < 4; ++i){
    const int ra = wr*64 + i*16 + l15;
    offA[i] = ra*32 + ((q ^ ((ra >> 1) & 3)) << 3);
    const int rb = wc*64 + i*16 + l15;
    offB[i] = rb*32 + ((q ^ ((rb >> 1) & 3)) << 3);
  }

  for (int kt = 0; kt < K; kt += 32){
    gl2lds16(Abh + (size_t)r0*lda + kt + cs, &sAh[tid*8]);
    gl2lds16(Abh + (size_t)r1*lda + kt + cs, &sAh[2048 + tid*8]);
    gl2lds16(Abl + (size_t)r0*lda + kt + cs, &sAl[tid*8]);
    gl2lds16(Abl + (size_t)r1*lda + kt + cs, &sAl[2048 + tid*8]);
    gl2lds16(Bbh + (size_t)r0*ldb + kt + cs, &sBh[tid*8]);
    gl2lds16(Bbh + (size_t)r1*ldb + kt + cs, &sBh[2048 + tid*8]);
    gl2lds16(Bbl + (size_t)r0*ldb + kt + cs, &sBl[tid*8]);
    gl2lds16(Bbl + (size_t)r1*ldb + kt + cs, &sBl[2048 + tid*8]);
    __syncthreads();
    bf16x8 ah[4], al[4], bh2[4], bl2[4];
#pragma unroll
    for (int i = 0; i < 4; ++i){
      ah[i] = *(const bf16x8*)&sAh[offA[i]];
      al[i] = *(const bf16x8*)&sAl[offA[i]];
    }
#pragma unroll
    for (int j = 0; j < 4; ++j){
      bh2[j] = *(const bf16x8*)&sBh[offB[j]];
      bl2[j] = *(const bf16x8*)&sBl[offB[j]];
    }
#pragma unroll
    for (int i = 0; i < 4; ++i)
#pragma unroll
      for (int j = 0; j < 4; ++j){
        acc[i][j] = __builtin_amdgcn_mfma_f32_16x16x32_bf16(ah[i], bh2[j], acc[i][j], 0, 0, 0);
        acc[i][j] = __builtin_amdgcn_mfma_f32_16x16x32_bf16(ah[i], bl2[j], acc[i][j], 0, 0, 0);
        acc[i][j] = __builtin_amdgcn_mfma_f32_16x16x32_bf16(al[i], bh2[j], acc[i][j], 0, 0, 0);
      }
    __syncthreads();
  }

  const int rbase = blockIdx.x*128 + wr*64;
  const int cbase = blockIdx.y*128 + wc*64;

  if constexpr (EPI == 1){
    __shared__ float colpart[128];
    if (tid < 128) colpart[tid] = 0.f;
    __syncthreads();
#pragma unroll
    for (int j = 0; j < 4; ++j){
      const int gc = cbase + j*16 + l15;
      float lsum = 0.f;
#pragma unroll
      for (int i = 0; i < 4; ++i){
        const int gr0 = rbase + i*16 + q*4;
#pragma unroll
        for (int r = 0; r < 4; ++r){
          const float e = __expf(fminf(acc[i][j][r], 85.f));  // scores >= 0 (relu inputs)
          outF[(size_t)bb*ostr + (size_t)(gr0 + r)*ldo + gc] = e;
          lsum += e;
        }
      }
      atomicAdd(&colpart[wc*64 + j*16 + l15], lsum);
    }
    __syncthreads();
    if (tid < 128) atomicAdd(&colsum[(size_t)bb*NP + (size_t)blockIdx.y*128 + tid], colpart[tid]);
  } else {
#pragma unroll
    for (int j = 0; j < 4; ++j){
      const int gc = cbase + j*16 + l15;
      const float scale = pg[gc] * rsqrtf(pv[gc] + 1e-5f);
      const float bias  = pb[gc] - pm[gc]*scale;
#pragma unroll
      for (int i = 0; i < 4; ++i){
        const int gr0 = rbase + i*16 + q*4;
#pragma unroll
        for (int r = 0; r < 4; ++r){
          const size_t idx = (size_t)bb*ostr + (size_t)(gr0 + r)*ldo + gc;
          const float y = fmaxf(acc[i][j][r]*scale + bias, 0.f);
          const u16 h = f2bf(y);
          outH[idx] = h;
          outL[idx] = f2bf(y - bf2f(h));
        }
      }
    }
  }
}

// colinv[i] = 1 / colsum[i]
__global__ __launch_bounds__(256) void colinv_k(const float* __restrict__ cs,
                                                float* __restrict__ ci, int n){
  const int i = blockIdx.x*blockDim.x + threadIdx.x;
  if (i < n) ci[i] = 1.0f / cs[i];
}

// P[m][n] = expS[m][n]*colinv[n] (bf16); rs[m] = 1/(1e-9 + sum_n P_f32).
// One block per row m. b = blockIdx.x>>11 indexes colinv batch (0 for
// per-batch launches with pre-offset pointers).
__global__ __launch_bounds__(256) void normalize_rows(
    const float* __restrict__ expS, const float* __restrict__ colinv,
    u16* __restrict__ P, float* __restrict__ rs){
  const int mloc = blockIdx.x;
  const int b = mloc >> 11;
  const float* e  = expS  + (size_t)mloc * NP;
  const float* ci = colinv + (size_t)b * NP;
  const int t = threadIdx.x;
  float4 e0 = *(const float4*)&e[t*8];
  float4 e1 = *(const float4*)&e[t*8 + 4];
  float4 c0 = *(const float4*)&ci[t*8];
  float4 c1 = *(const float4*)&ci[t*8 + 4];
  float p0 = e0.x*c0.x, p1 = e0.y*c0.y, p2 = e0.z*c0.z, p3 = e0.w*c0.w;
  float p4 = e1.x*c1.x, p5 = e1.y*c1.y, p6 = e1.z*c1.z, p7 = e1.w*c1.w;
  ushort4 o0 = {f2bf(p0), f2bf(p1), f2bf(p2), f2bf(p3)};
  ushort4 o1 = {f2bf(p4), f2bf(p5), f2bf(p6), f2bf(p7)};
  *(ushort4*)&P[(size_t)mloc*NP + t*8]     = o0;
  *(ushort4*)&P[(size_t)mloc*NP + t*8 + 4] = o1;
  float s = ((p0+p1)+(p2+p3)) + ((p4+p5)+(p6+p7));
#pragma unroll
  for (int off2 = 32; off2; off2 >>= 1) s += __shfl_down(s, off2, 64);
  __shared__ float ws4[4];
  if ((t & 63) == 0) ws4[t >> 6] = s;
  __syncthreads();
  if (t == 0) rs[mloc] = 1.f / (1e-9f + ((ws4[0]+ws4[1]) + (ws4[2]+ws4[3])));
}

// ---------------------------------------------------------------------------
extern "C" void kernel_launch(void* const* d_in, const int* in_sizes, int n_in,
                              void* d_out, int out_size, void* d_ws, size_t ws_size,
                              hipStream_t stream){
  const float* x = (const float*)d_in[0];
  const float *W[5], *g[5], *bt[5], *mu[5], *vr[5];
  for (int i = 0; i < 5; ++i){
    W[i]  = (const float*)d_in[1 + 5*i + 0];
    g[i]  = (const float*)d_in[1 + 5*i + 1];
    bt[i] = (const float*)d_in[1 + 5*i + 2];
    mu[i] = (const float*)d_in[1 + 5*i + 3];
    vr[i] = (const float*)d_in[1 + 5*i + 4];
  }

  char* wp = (char*)d_ws;
  size_t off = 0;
  auto take = [&](size_t bytes) -> void* {
    void* p = wp + off;
    off = (off + bytes + 255) & ~(size_t)255;
    return p;
  };
  u16*   xh   = (u16*)take(33554432);   // x^T hi [b][n][c]; reused as v [b][c][n]
  u16*   xl   = (u16*)take(33554432);   // x^T lo;           reused as t [b][m][c]
  u16*   x1h  = (u16*)take(33554432);
  u16*   x1l  = (u16*)take(33554432);
  u16*   qkh  = (u16*)take(8388608);    // [b][n][256]: cols 0-127=q, 128-255=k
  u16*   qkl  = (u16*)take(8388608);
  float* S    = (float*)take(16777216); // per-batch expS fp32 [2048][2048]
  float* csum = (float*)take(65536);    // colsum [b][n]
  float* cinv = (float*)take(65536);
  float* rs   = (float*)take(65536);
  u16*   w1h  = (u16*)take(2097152);
  u16*   w1l  = (u16*)take(2097152);
  u16*   w2h  = (u16*)take(2097152);
  u16*   w34h = (u16*)take(524288);     // [256][1024] stacked W3;W4
  u16*   w34l = (u16*)take(524288);
  u16*   w5h  = (u16*)take(2097152);
  float* p34  = (float*)take(4096);     // g34|b34|m34|v34

  if (ws_size < off){
    ws_marker<<<1, 1, 0, stream>>>((float*)d_out, (float)(ws_size >> 20));
    return;
  }

  // Batched stats path if an 8-batch expS fits (ws_size is per-session
  // constant -> identical work every call, graph-safe).
  float* expS_all = nullptr;
  const size_t need = (size_t)8 * NP * NP * 4;
  if (ws_size >= off + need) expS_all = (float*)take(need);

  u16* vh = xh;            // x dead after conv1
  u16* tt = xl;
  u16* P  = (u16*)d_out;   // 64 MiB bf16, fully overwritten by conv5 later

  prep_all<<<dim3(256, 7), 256, 0, stream>>>(
      W[0], W[1], W[2], W[3], W[4],
      w1h, w1l, w2h, w34h, w34l, w5h,
      g[2], bt[2], mu[2], vr[2], g[3], bt[3], mu[3], vr[3],
      p34, csum);

  transpose_split<<<dim3(32,16,8), 256, 0, stream>>>(x, xh, xl);

  // conv1: x1 = cbr(x, W1)  (split precision)
  gemm_split3<0><<<dim3(16,8,8), 256, 0, stream>>>(
      xh, xl, w1h, w1l, CH, CH, (long)NP*CH, 0, CH,
      x1h, x1l, nullptr, (long)NP*CH, CH, g[0], bt[0], mu[0], vr[0], nullptr);

  // conv3+conv4 fused: qk[b][n][256] (split precision)
  gemm_split3<0><<<dim3(16,2,8), 256, 0, stream>>>(
      x1h, x1l, w34h, w34l, CH, CH, (long)NP*CH, 0, CH,
      qkh, qkl, nullptr, (long)NP*256, 256, p34, p34+256, p34+512, p34+768, nullptr);

  if (expS_all){
    gemm_split3<1><<<dim3(16,16,8), 256, 0, stream>>>(
        qkh + 128, qkl + 128, qkh, qkl, 256, 256, (long)NP*256, (long)NP*256, CQ,
        nullptr, nullptr, expS_all, (long)NP*NP, NP,
        nullptr, nullptr, nullptr, nullptr, csum);
    colinv_k<<<dim3(64), 256, 0, stream>>>(csum, cinv, 8*NP);
    normalize_rows<<<dim3(8*NP), 256, 0, stream>>>(expS_all, cinv, P, rs);
  } else {
    for (int b = 0; b < 8; ++b){
      const size_t qo = (size_t)b*NP*256;
      gemm_split3<1><<<dim3(16,16,1), 256, 0, stream>>>(
          qkh + qo + 128, qkl + qo + 128, qkh + qo, qkl + qo, 256, 256, 0, 0, CQ,
          nullptr, nullptr, S, 0, NP,
          nullptr, nullptr, nullptr, nullptr, csum + b*NP);
      colinv_k<<<dim3(8), 256, 0, stream>>>(csum + b*NP, cinv + b*NP, NP);
      normalize_rows<<<dim3(NP), 256, 0, stream>>>(
          S, cinv + b*NP, P + (size_t)b*NP*NP, rs + b*NP);
    }
  }

  // conv2: v = cbr(x1, W2) -> vh [b][c][n]
  gemm_plain<0><<<dim3(16,8,8), 256, 0, stream>>>(
      x1h, w2h, CH, CH, (long)NP*CH, 0, CH,
      vh, (long)CH*NP, NP, g[1], bt[1], mu[1], vr[1], nullptr, nullptr, nullptr);

  // attn + t = x1 - attn*rscale -> tt [b][m][c]
  gemm_plain<1><<<dim3(16,8,8), 256, 0, stream>>>(
      P, vh, NP, NP, (long)NP*NP, (long)CH*NP, NP,
      tt, (long)NP*CH, CH, nullptr, nullptr, nullptr, nullptr, x1h, x1l, rs);

  // conv5 + residual -> d_out fp32 [b][c][n]
  gemm_plain<2><<<dim3(16,8,8), 256, 0, stream>>>(
      tt, w5h, CH, CH, (long)NP*CH, 0, CH,
      d_out, (long)CH*NP, NP, g[4], bt[4], mu[4], vr[4], x1h, x1l, nullptr);
}

// Round 5
// 670.085 us; speedup vs baseline: 1.9835x; 1.2178x over previous
//
#include <hip/hip_runtime.h>

typedef unsigned short u16;
using bf16x8 = __attribute__((ext_vector_type(8))) short;
using f32x4  = __attribute__((ext_vector_type(4))) float;

#define CH   1024
#define NP   2048
#define CQ   128

__device__ __forceinline__ float bf2f(u16 u){
  union { unsigned u; float f; } c; c.u = ((unsigned)u) << 16; return c.f;
}
__device__ __forceinline__ u16 f2bf(float f){
  unsigned x = __float_as_uint(f);
  unsigned r = (x + 0x7fffu + ((x >> 16) & 1u)) >> 16;
  return (u16)r;
}

__device__ __forceinline__ void gl2lds16(const u16* g, u16* l){
  __builtin_amdgcn_global_load_lds(
      (const __attribute__((address_space(1))) unsigned int*)(const void*)g,
      (__attribute__((address_space(3))) unsigned int*)(void*)l,
      16, 0, 0);
}

__global__ void ws_marker(float* out, float have_mb){
  out[0] = 1048576.0f + have_mb;
}

// ---------------------------------------------------------------------------
// Transpose+split: x [b][c][n] fp32 -> xh,xl [b][n][c] bf16 (hi/lo split)
// ---------------------------------------------------------------------------
__global__ __launch_bounds__(256) void transpose_split(const float* __restrict__ x,
                                                       u16* __restrict__ xh,
                                                       u16* __restrict__ xl){
  const int bb = blockIdx.z;
  const int n0 = blockIdx.x * 64, c0 = blockIdx.y * 64;
  __shared__ float tile[64][65];
  const int t = threadIdx.x;
  const float* xb = x + ((size_t)bb*CH + c0)*NP + n0;
#pragma unroll
  for (int rr = 0; rr < 4; ++rr){
    const int c_l = (t >> 4) + rr*16;
    const int n_l = (t & 15) * 4;
    float4 v = *(const float4*)&xb[(size_t)c_l*NP + n_l];
    tile[c_l][n_l+0] = v.x; tile[c_l][n_l+1] = v.y;
    tile[c_l][n_l+2] = v.z; tile[c_l][n_l+3] = v.w;
  }
  __syncthreads();
  u16* oh = xh + ((size_t)bb*NP + n0)*CH + c0;
  u16* ol = xl + ((size_t)bb*NP + n0)*CH + c0;
#pragma unroll
  for (int rr = 0; rr < 4; ++rr){
    const int n_l = (t >> 4) + rr*16;
    const int c_l = (t & 15) * 4;
    ushort4 h, l;
    float v0 = tile[c_l+0][n_l], v1 = tile[c_l+1][n_l];
    float v2 = tile[c_l+2][n_l], v3 = tile[c_l+3][n_l];
    h.x = f2bf(v0); l.x = f2bf(v0 - bf2f(h.x));
    h.y = f2bf(v1); l.y = f2bf(v1 - bf2f(h.y));
    h.z = f2bf(v2); l.z = f2bf(v2 - bf2f(h.z));
    h.w = f2bf(v3); l.w = f2bf(v3 - bf2f(h.w));
    *(ushort4*)&oh[(size_t)n_l*CH + c_l] = h;
    *(ushort4*)&ol[(size_t)n_l*CH + c_l] = l;
  }
}

// ---------------------------------------------------------------------------
// Prep: weight splits (w3/w4 stacked), BN-param concat, colsum zero.
// grid.y = segment 0..6
// ---------------------------------------------------------------------------
__global__ __launch_bounds__(256) void prep_all(
    const float* __restrict__ w0, const float* __restrict__ w1,
    const float* __restrict__ w2, const float* __restrict__ w3,
    const float* __restrict__ w4,
    u16* w1h, u16* w1l, u16* w2h,
    u16* w34h, u16* w34l, u16* w5h,
    const float* g3, const float* b3, const float* m3, const float* v3,
    const float* g4, const float* b4, const float* m4, const float* v4,
    float* p34, float* colsum){
  const int seg = blockIdx.y;
  if (seg == 5){
    for (int i = blockIdx.x*blockDim.x + threadIdx.x; i < 1024; i += gridDim.x*blockDim.x){
      const int grp = i >> 8, j = i & 255;
      const float* pa = (grp==0) ? g3 : (grp==1) ? b3 : (grp==2) ? m3 : v3;
      const float* pb = (grp==0) ? g4 : (grp==1) ? b4 : (grp==2) ? m4 : v4;
      p34[i] = (j < 128) ? pa[j] : pb[j-128];
    }
    return;
  }
  if (seg == 6){
    for (int i = blockIdx.x*blockDim.x + threadIdx.x; i < 8*NP; i += gridDim.x*blockDim.x)
      colsum[i] = 0.f;
    return;
  }
  const float* w; u16 *wh, *wl; int n;
  switch (seg){
    case 0:  w = w0; wh = w1h;           wl = w1l;           n = CH*CH; break;
    case 1:  w = w1; wh = w2h;           wl = nullptr;       n = CH*CH; break;
    case 2:  w = w2; wh = w34h;          wl = w34l;          n = CQ*CH; break;
    case 3:  w = w3; wh = w34h + CQ*CH;  wl = w34l + CQ*CH;  n = CQ*CH; break;
    default: w = w4; wh = w5h;           wl = nullptr;       n = CH*CH; break;
  }
  for (int i = blockIdx.x*blockDim.x + threadIdx.x; i < n; i += gridDim.x*blockDim.x){
    float v = w[i];
    u16 h = f2bf(v);
    wh[i] = h;
    if (wl) wl[i] = f2bf(v - bf2f(h));
  }
}

// ---------------------------------------------------------------------------
// Plain bf16 GEMM, BT-form operands, 128x128 tile, BK=64.
// 1-D grid, XCD swizzle: bb = id&7 (one batch per XCD), y fastest within XCD.
// EPI 0: BN+relu (*cinv[row] col-div fold), bf16 store out[b][col][row] (conv2)
// EPI 1: attn: extra MFMA vs colinv-fragment accumulates rowsum; epilogue
//        t = x1 - acc/(1e-9+rowsum), bf16 row-major out[b][row][col]
// EPI 2: BN+relu + x1 residual, fp32 store out[b][col][row]           (conv5)
// ---------------------------------------------------------------------------
template<int EPI>
__global__ __launch_bounds__(256, 4) void gemm_plain(
    const u16* __restrict__ A, const u16* __restrict__ B,
    int lda, int ldb, long astr, long bstr, int K,
    void* __restrict__ out0, long ostr, int ldo,
    const float* __restrict__ pg, const float* __restrict__ pb,
    const float* __restrict__ pm, const float* __restrict__ pv,
    const u16* __restrict__ x1h, const u16* __restrict__ x1l,
    const float* __restrict__ cinv, const u16* __restrict__ cbf)
{
  __shared__ __align__(16) u16 sA[8192], sB[8192];   // 128 rows x 64 k
  const int tid  = threadIdx.x;
  const int lane = tid & 63, wave = tid >> 6;
  const int wr = wave & 1, wc = wave >> 1;
  const int l15 = lane & 15, q = lane >> 4;
  const int id = blockIdx.x;
  const int bb = id & 7;
  const int rest = id >> 3;
  const int by = rest & 7;
  const int bx = rest >> 3;
  const u16* Ab = A + (size_t)bb*astr + (size_t)bx*128*lda;
  const u16* Bb = B + (size_t)bb*bstr + (size_t)by*128*ldb;

  f32x4 acc[4][4] = {};
  f32x4 accR[4] = {};   // EPI 1 rowsum accumulator

  const int srow = tid >> 3;
  const int schunk = tid & 7;

  for (int kt = 0; kt < K; kt += 64){
#pragma unroll
    for (int r = 0; r < 4; ++r){
      const int row = r*32 + srow;
      const int gc8 = ((schunk ^ (row & 7)) << 3);
      gl2lds16(Ab + (size_t)row*lda + kt + gc8, &sA[r*2048 + tid*8]);
      gl2lds16(Bb + (size_t)row*ldb + kt + gc8, &sB[r*2048 + tid*8]);
    }
    __syncthreads();
#pragma unroll
    for (int s = 0; s < 2; ++s){
      bf16x8 af[4], bfr[4];
#pragma unroll
      for (int i = 0; i < 4; ++i){
        const int ra = wr*64 + i*16 + l15;
        af[i]  = *(const bf16x8*)&sA[ra*64 + (((s*4 + q) ^ (ra & 7)) << 3)];
        const int rb = wc*64 + i*16 + l15;
        bfr[i] = *(const bf16x8*)&sB[rb*64 + (((s*4 + q) ^ (rb & 7)) << 3)];
      }
      if constexpr (EPI == 1){
        // rowsum: B[col][k] = colinv[k] for every col -> D = sum_k A*colinv
        const bf16x8 bcs = *(const bf16x8*)&cbf[(size_t)bb*NP + kt + s*32 + q*8];
#pragma unroll
        for (int i = 0; i < 4; ++i)
          accR[i] = __builtin_amdgcn_mfma_f32_16x16x32_bf16(af[i], bcs, accR[i], 0, 0, 0);
      }
#pragma unroll
      for (int i = 0; i < 4; ++i)
#pragma unroll
        for (int j = 0; j < 4; ++j)
          acc[i][j] = __builtin_amdgcn_mfma_f32_16x16x32_bf16(af[i], bfr[j], acc[i][j], 0, 0, 0);
    }
    __syncthreads();
  }

  const int rbase = bx*128 + wr*64;
  const int cbase = by*128 + wc*64;
#pragma unroll
  for (int j = 0; j < 4; ++j){
    const int gc = cbase + j*16 + l15;
    float scale = 0.f, bias = 0.f;
    if (EPI == 0 || EPI == 2){
      scale = pg[gc] * rsqrtf(pv[gc] + 1e-5f);
      bias  = pb[gc] - pm[gc]*scale;
    }
#pragma unroll
    for (int i = 0; i < 4; ++i){
      const int gr0 = rbase + i*16 + q*4;
      if (EPI == 0){
        const float4 cv = *(const float4*)&cinv[(size_t)bb*NP + gr0];
        ushort4 pk;
        pk.x = f2bf(fmaxf(acc[i][j][0]*scale + bias, 0.f) * cv.x);
        pk.y = f2bf(fmaxf(acc[i][j][1]*scale + bias, 0.f) * cv.y);
        pk.z = f2bf(fmaxf(acc[i][j][2]*scale + bias, 0.f) * cv.z);
        pk.w = f2bf(fmaxf(acc[i][j][3]*scale + bias, 0.f) * cv.w);
        *(ushort4*)&((u16*)out0)[(size_t)bb*ostr + (size_t)gc*ldo + gr0] = pk;
      } else if (EPI == 1){
#pragma unroll
        for (int r = 0; r < 4; ++r){
          const int gr = gr0 + r;
          const size_t idx = (size_t)bb*ostr + (size_t)gr*ldo + gc;
          const float rsv = 1.f / (1e-9f + accR[i][r]);
          const float x1v = bf2f(x1h[idx]) + bf2f(x1l[idx]);
          ((u16*)out0)[idx] = f2bf(x1v - acc[i][j][r]*rsv);
        }
      } else {
        float4 o4;
#pragma unroll
        for (int r = 0; r < 4; ++r){
          const int gr = gr0 + r;
          const size_t xidx = (size_t)bb*((size_t)NP*CH) + (size_t)gr*CH + gc;
          const float x2  = fmaxf(acc[i][j][r]*scale + bias, 0.f);
          const float x1v = bf2f(x1h[xidx]) + bf2f(x1l[xidx]);
          (&o4.x)[r] = x1v + x2;
        }
        *(float4*)&((float*)out0)[(size_t)bb*ostr + (size_t)gc*ldo + gr0] = o4;
      }
    }
  }
}

// ---------------------------------------------------------------------------
// Split-bf16 GEMM: acc = Ah*Bh + Ah*Bl + Al*Bh (~fp32 accuracy). BK=32.
// 1-D grid, XCD swizzle (gymask/gyshift = y-dim decode).
// EPI 0: BN+relu, split bf16 store row-major (conv1 / conv34)
// EPI 1: expS = exp(acc) -> bf16 store + per-column sum atomics (scores)
// ---------------------------------------------------------------------------
template<int EPI>
__global__ __launch_bounds__(256, 4) void gemm_split3(
    const u16* __restrict__ Ah, const u16* __restrict__ Al,
    const u16* __restrict__ Bh, const u16* __restrict__ Bl,
    int lda, int ldb, long astr, long bstr, int K,
    u16* __restrict__ outH, u16* __restrict__ outL,
    long ostr, int ldo,
    const float* __restrict__ pg, const float* __restrict__ pb,
    const float* __restrict__ pm, const float* __restrict__ pv,
    float* __restrict__ colsum, int gymask, int gyshift)
{
  __shared__ __align__(16) u16 sAh[4096], sAl[4096], sBh[4096], sBl[4096];
  const int tid  = threadIdx.x;
  const int lane = tid & 63, wave = tid >> 6;
  const int wr = wave & 1, wc = wave >> 1;
  const int l15 = lane & 15, q = lane >> 4;
  const int id = blockIdx.x;
  const int bb = id & 7;
  const int rest = id >> 3;
  const int by = rest & gymask;
  const int bx = rest >> gyshift;
  const u16* Abh = Ah + (size_t)bb*astr + (size_t)bx*128*lda;
  const u16* Abl = Al + (size_t)bb*astr + (size_t)bx*128*lda;
  const u16* Bbh = Bh + (size_t)bb*bstr + (size_t)by*128*ldb;
  const u16* Bbl = Bl + (size_t)bb*bstr + (size_t)by*128*ldb;

  f32x4 acc[4][4] = {};

  const int r0 = tid >> 2, r1 = r0 + 64;
  const int cs = (((tid & 3) ^ ((r0 >> 1) & 3)) << 3);

  int offA[4], offB[4];
#pragma unroll
  for (int i = 0; i < 4; ++i){
    const int ra = wr*64 + i*16 + l15;
    offA[i] = ra*32 + ((q ^ ((ra >> 1) & 3)) << 3);
    const int rb = wc*64 + i*16 + l15;
    offB[i] = rb*32 + ((q ^ ((rb >> 1) & 3)) << 3);
  }

  for (int kt = 0; kt < K; kt += 32){
    gl2lds16(Abh + (size_t)r0*lda + kt + cs, &sAh[tid*8]);
    gl2lds16(Abh + (size_t)r1*lda + kt + cs, &sAh[2048 + tid*8]);
    gl2lds16(Abl + (size_t)r0*lda + kt + cs, &sAl[tid*8]);
    gl2lds16(Abl + (size_t)r1*lda + kt + cs, &sAl[2048 + tid*8]);
    gl2lds16(Bbh + (size_t)r0*ldb + kt + cs, &sBh[tid*8]);
    gl2lds16(Bbh + (size_t)r1*ldb + kt + cs, &sBh[2048 + tid*8]);
    gl2lds16(Bbl + (size_t)r0*ldb + kt + cs, &sBl[tid*8]);
    gl2lds16(Bbl + (size_t)r1*ldb + kt + cs, &sBl[2048 + tid*8]);
    __syncthreads();
    bf16x8 ah[4], al[4], bh2[4], bl2[4];
#pragma unroll
    for (int i = 0; i < 4; ++i){
      ah[i] = *(const bf16x8*)&sAh[offA[i]];
      al[i] = *(const bf16x8*)&sAl[offA[i]];
    }
#pragma unroll
    for (int j = 0; j < 4; ++j){
      bh2[j] = *(const bf16x8*)&sBh[offB[j]];
      bl2[j] = *(const bf16x8*)&sBl[offB[j]];
    }
#pragma unroll
    for (int i = 0; i < 4; ++i)
#pragma unroll
      for (int j = 0; j < 4; ++j){
        acc[i][j] = __builtin_amdgcn_mfma_f32_16x16x32_bf16(ah[i], bh2[j], acc[i][j], 0, 0, 0);
        acc[i][j] = __builtin_amdgcn_mfma_f32_16x16x32_bf16(ah[i], bl2[j], acc[i][j], 0, 0, 0);
        acc[i][j] = __builtin_amdgcn_mfma_f32_16x16x32_bf16(al[i], bh2[j], acc[i][j], 0, 0, 0);
      }
    __syncthreads();
  }

  const int rbase = bx*128 + wr*64;
  const int cbase = by*128 + wc*64;

  if constexpr (EPI == 1){
    __shared__ float colpart[128];
    if (tid < 128) colpart[tid] = 0.f;
    __syncthreads();
#pragma unroll
    for (int j = 0; j < 4; ++j){
      const int gc = cbase + j*16 + l15;
      float lsum = 0.f;
#pragma unroll
      for (int i = 0; i < 4; ++i){
        const int gr0 = rbase + i*16 + q*4;
#pragma unroll
        for (int r = 0; r < 4; ++r){
          const float e = __expf(fminf(acc[i][j][r], 85.f));  // scores >= 0
          outH[(size_t)bb*ostr + (size_t)(gr0 + r)*ldo + gc] = f2bf(e);
          lsum += e;
        }
      }
      atomicAdd(&colpart[wc*64 + j*16 + l15], lsum);
    }
    __syncthreads();
    if (tid < 128) atomicAdd(&colsum[(size_t)bb*NP + (size_t)by*128 + tid], colpart[tid]);
  } else {
#pragma unroll
    for (int j = 0; j < 4; ++j){
      const int gc = cbase + j*16 + l15;
      const float scale = pg[gc] * rsqrtf(pv[gc] + 1e-5f);
      const float bias  = pb[gc] - pm[gc]*scale;
#pragma unroll
      for (int i = 0; i < 4; ++i){
        const int gr0 = rbase + i*16 + q*4;
#pragma unroll
        for (int r = 0; r < 4; ++r){
          const size_t idx = (size_t)bb*ostr + (size_t)(gr0 + r)*ldo + gc;
          const float y = fmaxf(acc[i][j][r]*scale + bias, 0.f);
          const u16 h = f2bf(y);
          outH[idx] = h;
          outL[idx] = f2bf(y - bf2f(h));
        }
      }
    }
  }
}

// colinv = 1/colsum (fp32 + bf16 copies)
__global__ __launch_bounds__(256) void colinv_k(const float* __restrict__ cs,
                                                float* __restrict__ ci,
                                                u16* __restrict__ cib, int n){
  const int i = blockIdx.x*blockDim.x + threadIdx.x;
  if (i < n){
    const float v = 1.0f / cs[i];
    ci[i]  = v;
    cib[i] = f2bf(v);
  }
}

// ---------------------------------------------------------------------------
extern "C" void kernel_launch(void* const* d_in, const int* in_sizes, int n_in,
                              void* d_out, int out_size, void* d_ws, size_t ws_size,
                              hipStream_t stream){
  const float* x = (const float*)d_in[0];
  const float *W[5], *g[5], *bt[5], *mu[5], *vr[5];
  for (int i = 0; i < 5; ++i){
    W[i]  = (const float*)d_in[1 + 5*i + 0];
    g[i]  = (const float*)d_in[1 + 5*i + 1];
    bt[i] = (const float*)d_in[1 + 5*i + 2];
    mu[i] = (const float*)d_in[1 + 5*i + 3];
    vr[i] = (const float*)d_in[1 + 5*i + 4];
  }

  char* wp = (char*)d_ws;
  size_t off = 0;
  auto take = [&](size_t bytes) -> void* {
    void* p = wp + off;
    off = (off + bytes + 255) & ~(size_t)255;
    return p;
  };
  u16*   xh   = (u16*)take(33554432);   // x^T hi [b][n][c]; reused as v' [b][c][n]
  u16*   xl   = (u16*)take(33554432);   // x^T lo;           reused as t [b][m][c]
  u16*   x1h  = (u16*)take(33554432);
  u16*   x1l  = (u16*)take(33554432);
  u16*   qkh  = (u16*)take(8388608);    // [b][n][256]: cols 0-127=q, 128-255=k
  u16*   qkl  = (u16*)take(8388608);
  float* csum = (float*)take(65536);    // colsum [b][n]
  float* cinv = (float*)take(65536);    // fp32 1/colsum
  u16*   cibf = (u16*)take(32768);      // bf16 1/colsum
  u16*   w1h  = (u16*)take(2097152);
  u16*   w1l  = (u16*)take(2097152);
  u16*   w2h  = (u16*)take(2097152);
  u16*   w34h = (u16*)take(524288);     // [256][1024] stacked W3;W4
  u16*   w34l = (u16*)take(524288);
  u16*   w5h  = (u16*)take(2097152);
  float* p34  = (float*)take(4096);     // g34|b34|m34|v34

  if (ws_size < off){
    ws_marker<<<1, 1, 0, stream>>>((float*)d_out, (float)(ws_size >> 20));
    return;
  }

  u16* vh   = xh;            // x dead after conv1
  u16* tt   = xl;
  u16* expS = (u16*)d_out;   // 64 MiB bf16 = d_out exactly; overwritten by conv5

  prep_all<<<dim3(256, 7), 256, 0, stream>>>(
      W[0], W[1], W[2], W[3], W[4],
      w1h, w1l, w2h, w34h, w34l, w5h,
      g[2], bt[2], mu[2], vr[2], g[3], bt[3], mu[3], vr[3],
      p34, csum);

  transpose_split<<<dim3(32,16,8), 256, 0, stream>>>(x, xh, xl);

  // conv1: x1 = cbr(x, W1)  (split precision)   grid 16x8x8
  gemm_split3<0><<<dim3(1024), 256, 0, stream>>>(
      xh, xl, w1h, w1l, CH, CH, (long)NP*CH, 0, CH,
      x1h, x1l, (long)NP*CH, CH, g[0], bt[0], mu[0], vr[0], nullptr, 7, 3);

  // conv3+conv4 fused: qk[b][n][256]             grid 16x2x8
  gemm_split3<0><<<dim3(256), 256, 0, stream>>>(
      x1h, x1l, w34h, w34l, CH, CH, (long)NP*CH, 0, CH,
      qkh, qkl, (long)NP*256, 256, p34, p34+256, p34+512, p34+768, nullptr, 1, 1);

  // scores: expS[b][m][n] = exp(k_m . q_n) bf16 + column sums   grid 16x16x8
  gemm_split3<1><<<dim3(2048), 256, 0, stream>>>(
      qkh + 128, qkl + 128, qkh, qkl, 256, 256, (long)NP*256, (long)NP*256, CQ,
      expS, nullptr, (long)NP*NP, NP,
      nullptr, nullptr, nullptr, nullptr, csum, 15, 4);

  colinv_k<<<dim3(64), 256, 0, stream>>>(csum, cinv, cibf, 8*NP);

  // conv2: v' = cbr(x1, W2) * colinv[n]  -> vh [b][c][n]        grid 16x8x8
  gemm_plain<0><<<dim3(1024), 256, 0, stream>>>(
      x1h, w2h, CH, CH, (long)NP*CH, 0, CH,
      vh, (long)CH*NP, NP, g[1], bt[1], mu[1], vr[1],
      nullptr, nullptr, cinv, nullptr);

  // attn: acc = expS . v'; rowsum via colinv-MFMA; t = x1 - acc/rowsum
  gemm_plain<1><<<dim3(1024), 256, 0, stream>>>(
      expS, vh, NP, NP, (long)NP*NP, (long)CH*NP, NP,
      tt, (long)NP*CH, CH, nullptr, nullptr, nullptr, nullptr,
      x1h, x1l, nullptr, cibf);

  // conv5 + residual -> d_out fp32 [b][c][n]
  gemm_plain<2><<<dim3(1024), 256, 0, stream>>>(
      tt, w5h, CH, CH, (long)NP*CH, 0, CH,
      d_out, (long)CH*NP, NP, g[4], bt[4], mu[4], vr[4],
      x1h, x1l, nullptr, nullptr);
}